// Round 7
// baseline (29.073 us; speedup 1.0000x reference)
//
#include <hip/hip_runtime.h>
#include <hip/hip_bf16.h>
#include <math.h>

// out[b,c,y,x] = (1/50)*albedo * sum_m relu(n.l_m)*env*sin(phi_i)
// Antipodal pairing (i,j)<->(16-i,(j+16)&31):
//   light = n.W + sum_{256 slots} |n.l_s| * hs_s   (invalid slots have hs=0;
//   0.5/50 folded into hs and W).  Factorized dot:
//   d(i,j) = sp_i*(nx*st_j - nz*ct_j) + ny*cp_i,  trig constexpr / tiny table.
// MFMA: O^T(3ch x 16pix) += H^T(3 x 256) * P(256 x 16) via 8x
//   mfma_f32_16x16x32_bf16.  P is produced DIRECTLY in B-frag layout:
//   lane&15 = pixel col, lane>>4 = k-chunk -> lane computes the 8 i-values of
//   one j for its pixel (no cross-lane data movement).  d stays fp32; only
//   |d| and H are bf16 (precision: ~5e-3 vs 2.9e-2 threshold).

constexpr int HW     = 512 * 512;
constexpr int WAVES  = 4;
constexpr int GROUPS = 8;     // 16-pixel groups per wave

typedef short short8 __attribute__((ext_vector_type(8)));
typedef float f32x4  __attribute__((ext_vector_type(4)));

// sin/cos((e+1)*pi/16), e = 0..7  (i = e+1)
__device__ constexpr float SP[8] = {
    0.195090322f, 0.382683432f, 0.555570233f, 0.707106781f,
    0.831469612f, 0.923879533f, 0.980785280f, 1.0f };
__device__ constexpr float CP[8] = {
    0.980785280f, 0.923879533f, 0.831469612f, 0.707106781f,
    0.555570233f, 0.382683432f, 0.195090322f, 0.0f };

union bfu { __hip_bfloat16 h; short s; };
__device__ __forceinline__ short f2bf(float x) {
    bfu u; u.h = __float2bfloat16(x); return u.s;
}

__global__ __launch_bounds__(256)
void build_tab_kernel(const float* __restrict__ env,
                      float2* __restrict__ jt,      // [32] (st, ct)
                      short8* __restrict__ hf,      // [B][8 tiles][64 lanes]
                      float*  __restrict__ Wout)    // [B][9]
{
    const int b = blockIdx.x;
    const int t = threadIdx.x;

    if (b == 0 && t < 32) {
        const float th = (float)t * 0.19634954084936207f;  // j*pi/16
        jt[t] = make_float2(sinf(th), cosf(th));
    }

    // H^T fragments in A-operand layout: slot s=(tile,lane); lane&15=channel,
    // lane>>4=k-chunk -> j = tile*4 + (lane>>4); element e -> i = e+1.
    for (int s = t; s < 512; s += 256) {
        const int tile = s >> 6, lane = s & 63;
        const int c = lane >> 4, ch = lane & 15;
        const int j = tile * 4 + c;
        short8 f;
        #pragma unroll
        for (int e = 0; e < 8; ++e) {
            const int i = e + 1;
            float v = 0.f;
            if (ch < 3 && !(i == 8 && j >= 16)) {            // valid pair slot
                const int i2 = 16 - i, j2 = (j + 16) & 31;
                const float sp = sinf((float)i * 0.19634954084936207f);
                v = (env[((size_t)(b * 16 + i ) * 32 + j ) * 3 + ch] +
                     env[((size_t)(b * 16 + i2) * 32 + j2) * 3 + ch]) * sp * 0.01f;
            }
            f[e] = f2bf(v);
        }
        hf[(size_t)b * 512 + s] = f;
    }

    // W = sum_pairs l_a (h_a - h_b)^T, scaled by sin(phi)*0.01 (fp32, exact)
    __shared__ float Wred[4][9];
    float W[9];
    #pragma unroll
    for (int q = 0; q < 9; ++q) W[q] = 0.0f;

    if (t < 240) {
        int i, j;
        if (t < 224) { i = 1 + (t >> 5); j = t & 31; }
        else         { i = 8;            j = t - 224; }
        const int i2 = 16 - i, j2 = (j + 16) & 31;
        const float phi   = (float)i * 0.19634954084936207f;
        const float theta = (float)j * 0.19634954084936207f;
        const float sp = sinf(phi),   cp = cosf(phi);
        const float st = sinf(theta), ct = cosf(theta);
        const float dx = st * sp, dy = cp, dz = -ct * sp;    // |l| = 1
        const float scale = sp * 0.01f;
        const float* ea = env + ((size_t)(b * 16 + i ) * 32 + j ) * 3;
        const float* eb = env + ((size_t)(b * 16 + i2) * 32 + j2) * 3;
        const float hd0 = (ea[0] - eb[0]) * scale;
        const float hd1 = (ea[1] - eb[1]) * scale;
        const float hd2 = (ea[2] - eb[2]) * scale;
        W[0] = dx * hd0; W[1] = dx * hd1; W[2] = dx * hd2;
        W[3] = dy * hd0; W[4] = dy * hd1; W[5] = dy * hd2;
        W[6] = dz * hd0; W[7] = dz * hd1; W[8] = dz * hd2;
    }
    #pragma unroll
    for (int q = 0; q < 9; ++q) {
        float v = W[q];
        #pragma unroll
        for (int off = 32; off > 0; off >>= 1) v += __shfl_down(v, off);
        if ((t & 63) == 0) Wred[t >> 6][q] = v;
    }
    __syncthreads();
    if (t < 9) Wout[b * 9 + t] = Wred[0][t] + Wred[1][t] + Wred[2][t] + Wred[3][t];
}

__global__ __launch_bounds__(256)
void env_render_kernel(const float*  __restrict__ normal,
                       const float*  __restrict__ albedo,
                       const float2* __restrict__ jt,
                       const short8* __restrict__ hf,
                       const float*  __restrict__ Wm,
                       float* __restrict__ out)
{
    const int b    = blockIdx.y;
    const int tid  = threadIdx.x;
    const int lane = tid & 63, wave = tid >> 6;
    const int ch   = lane & 15, cg = lane >> 4;   // pixel col / k-chunk (=j mod 4)

    // Per-wave invariants: H fragments + this lane's (st, ct) per tile
    short8 Hf[8];
    float  stj[8], ctj[8];
    #pragma unroll
    for (int tl = 0; tl < 8; ++tl) {
        Hf[tl] = hf[(size_t)b * 512 + tl * 64 + lane];
        const float2 jc = jt[tl * 4 + cg];        // j = tl*4 + cg
        stj[tl] = jc.x; ctj[tl] = jc.y;
    }
    float Wl[9];
    #pragma unroll
    for (int q = 0; q < 9; ++q) Wl[q] = Wm[b * 9 + q];

    const int g0 = (blockIdx.x * WAVES + wave) * GROUPS;

    for (int g = 0; g < GROUPS; ++g) {
        const int pix = (g0 + g) * 16 + ch;
        const float* p = normal + ((size_t)b * HW + pix) * 3;
        const float nx = fmaf(p[2], 2.0f, -1.0f);            // flip + decode
        const float ny = fmaf(p[1], 2.0f, -1.0f);
        const float nz = fmaf(p[0], 2.0f, -1.0f);

        float nyc[8];
        #pragma unroll
        for (int e = 0; e < 8; ++e) nyc[e] = ny * CP[e];

        f32x4 acc = {0.f, 0.f, 0.f, 0.f};
        #pragma unroll
        for (int tl = 0; tl < 8; ++tl) {
            const float u = fmaf(nx, stj[tl], -(nz * ctj[tl]));
            short8 P;
            #pragma unroll
            for (int e = 0; e < 8; ++e) {
                const float d = fmaf(SP[e], u, nyc[e]);      // fp32, exact
                P[e] = f2bf(fabsf(d));
            }
            acc = __builtin_amdgcn_mfma_f32_16x16x32_bf16(Hf[tl], P, acc, 0, 0, 0);
        }

        if (cg == 0) {   // lanes 0-15 hold rows 0-2 = channels, col = pixel
            const size_t base = (size_t)b * 3 * HW + pix;
            const float l0 = acc[0] + fmaf(nx, Wl[0], fmaf(ny, Wl[3], nz * Wl[6]));
            const float l1 = acc[1] + fmaf(nx, Wl[1], fmaf(ny, Wl[4], nz * Wl[7]));
            const float l2 = acc[2] + fmaf(nx, Wl[2], fmaf(ny, Wl[5], nz * Wl[8]));
            out[base]          = l0 * albedo[base];
            out[base + HW]     = l1 * albedo[base + HW];
            out[base + 2 * HW] = l2 * albedo[base + 2 * HW];
        }
    }
}

extern "C" void kernel_launch(void* const* d_in, const int* in_sizes, int n_in,
                              void* d_out, int out_size, void* d_ws, size_t ws_size,
                              hipStream_t stream)
{
    const float* env    = (const float*)d_in[0];
    const float* normal = (const float*)d_in[1];
    const float* albedo = (const float*)d_in[2];
    float* out          = (float*)d_out;
    char*  ws           = (char*)d_ws;

    const int B = in_sizes[0] / (16 * 32 * 3);               // = 2

    float2* jt   = (float2*)ws;                              // 256 B
    short8* hf   = (short8*)(ws + 256);                      // B*8192 B
    float*  Wmat = (float*)(ws + 256 + (size_t)B * 8192);    // B*9 floats

    build_tab_kernel<<<dim3(B), 256, 0, stream>>>(env, jt, hf, Wmat);

    // 16384 groups of 16 pixels per batch; 32 groups per block (4 waves x 8)
    dim3 grid((HW / 16) / (WAVES * GROUPS), B);              // (512, B)
    env_render_kernel<<<grid, 256, 0, stream>>>(normal, albedo, jt, hf, Wmat, out);
}

// Round 8
// 26.802 us; speedup vs baseline: 1.0847x; 1.0847x over previous
//
#include <hip/hip_runtime.h>
#include <hip/hip_bf16.h>
#include <math.h>

// out[b,c,y,x] = (1/50)*albedo * sum_m relu(n.l_m)*env*sin(phi_i)
// Antipodal pairing (i,j)<->(16-i,(j+16)&31):
//   light = n.W + sum_{256 slots} |n.l_s| * hs_s   (invalid slots hs=0;
//   0.5/50 folded into hs and W).  Factorized dot:
//   d(i,j) = sp_i*(nx*st_j - nz*ct_j) + ny*cp_i.
// MFMA: O^T(3ch x 16pix) += H^T(3 x 256) * P(256 x 16), 8x 16x16x32_bf16.
// P produced directly in B-frag layout (lane&15=pixel col, lane>>4=k-chunk);
// d stays fp32, only |d| and H are bf16.
// R8: fully-unrolled group loop + prologue prefetch of ALL normal/albedo
// loads (R7 was latency-bound: runtime loop exposed ~1.2k cyc/group).

constexpr int HW     = 512 * 512;
constexpr int WAVES  = 4;
constexpr int GROUPS = 4;     // 16-pixel groups per wave

typedef short short8 __attribute__((ext_vector_type(8)));
typedef float f32x4  __attribute__((ext_vector_type(4)));

// sin/cos((e+1)*pi/16), e = 0..7  (i = e+1)
__device__ constexpr float SP[8] = {
    0.195090322f, 0.382683432f, 0.555570233f, 0.707106781f,
    0.831469612f, 0.923879533f, 0.980785280f, 1.0f };
__device__ constexpr float CP[8] = {
    0.980785280f, 0.923879533f, 0.831469612f, 0.707106781f,
    0.555570233f, 0.382683432f, 0.195090322f, 0.0f };

union bfu { __hip_bfloat16 h; short s; };
__device__ __forceinline__ short f2bf(float x) {
    bfu u; u.h = __float2bfloat16(x); return u.s;
}

__global__ __launch_bounds__(256)
void build_tab_kernel(const float* __restrict__ env,
                      float2* __restrict__ jt,      // [32] (st, ct)
                      short8* __restrict__ hf,      // [B][8 tiles][64 lanes]
                      float*  __restrict__ Wout)    // [B][9]
{
    const int b = blockIdx.x;
    const int t = threadIdx.x;

    if (b == 0 && t < 32) {
        const float th = (float)t * 0.19634954084936207f;  // j*pi/16
        jt[t] = make_float2(sinf(th), cosf(th));
    }

    // H^T fragments in A-operand layout: lane&15=channel, lane>>4=k-chunk;
    // j = tile*4 + (lane>>4); element e -> i = e+1.
    for (int s = t; s < 512; s += 256) {
        const int tile = s >> 6, lane = s & 63;
        const int c = lane >> 4, ch = lane & 15;
        const int j = tile * 4 + c;
        short8 f;
        #pragma unroll
        for (int e = 0; e < 8; ++e) {
            const int i = e + 1;
            float v = 0.f;
            if (ch < 3 && !(i == 8 && j >= 16)) {            // valid pair slot
                const int i2 = 16 - i, j2 = (j + 16) & 31;
                const float sp = sinf((float)i * 0.19634954084936207f);
                v = (env[((size_t)(b * 16 + i ) * 32 + j ) * 3 + ch] +
                     env[((size_t)(b * 16 + i2) * 32 + j2) * 3 + ch]) * sp * 0.01f;
            }
            f[e] = f2bf(v);
        }
        hf[(size_t)b * 512 + s] = f;
    }

    // W = sum_pairs l_a (h_a - h_b)^T (fp32, exact)
    __shared__ float Wred[4][9];
    float W[9];
    #pragma unroll
    for (int q = 0; q < 9; ++q) W[q] = 0.0f;

    if (t < 240) {
        int i, j;
        if (t < 224) { i = 1 + (t >> 5); j = t & 31; }
        else         { i = 8;            j = t - 224; }
        const int i2 = 16 - i, j2 = (j + 16) & 31;
        const float phi   = (float)i * 0.19634954084936207f;
        const float theta = (float)j * 0.19634954084936207f;
        const float sp = sinf(phi),   cp = cosf(phi);
        const float st = sinf(theta), ct = cosf(theta);
        const float dx = st * sp, dy = cp, dz = -ct * sp;    // |l| = 1
        const float scale = sp * 0.01f;
        const float* ea = env + ((size_t)(b * 16 + i ) * 32 + j ) * 3;
        const float* eb = env + ((size_t)(b * 16 + i2) * 32 + j2) * 3;
        const float hd0 = (ea[0] - eb[0]) * scale;
        const float hd1 = (ea[1] - eb[1]) * scale;
        const float hd2 = (ea[2] - eb[2]) * scale;
        W[0] = dx * hd0; W[1] = dx * hd1; W[2] = dx * hd2;
        W[3] = dy * hd0; W[4] = dy * hd1; W[5] = dy * hd2;
        W[6] = dz * hd0; W[7] = dz * hd1; W[8] = dz * hd2;
    }
    #pragma unroll
    for (int q = 0; q < 9; ++q) {
        float v = W[q];
        #pragma unroll
        for (int off = 32; off > 0; off >>= 1) v += __shfl_down(v, off);
        if ((t & 63) == 0) Wred[t >> 6][q] = v;
    }
    __syncthreads();
    if (t < 9) Wout[b * 9 + t] = Wred[0][t] + Wred[1][t] + Wred[2][t] + Wred[3][t];
}

__global__ __launch_bounds__(256)
void env_render_kernel(const float*  __restrict__ normal,
                       const float*  __restrict__ albedo,
                       const float2* __restrict__ jt,
                       const short8* __restrict__ hf,
                       const float*  __restrict__ Wm,
                       float* __restrict__ out)
{
    const int b    = blockIdx.y;
    const int tid  = threadIdx.x;
    const int lane = tid & 63, wave = tid >> 6;
    const int ch   = lane & 15, cg = lane >> 4;   // pixel col / k-chunk (j mod 4)

    const int g0 = (blockIdx.x * WAVES + wave) * GROUPS;

    // ---- Prologue: issue ALL global loads up front (pipelined by vmcnt) ----
    float nr[GROUPS][3];     // raw normal values
    float al[GROUPS][3];     // albedo (4-way dup across cg -> coalescer dedups)
    #pragma unroll
    for (int g = 0; g < GROUPS; ++g) {
        const int pix = (g0 + g) * 16 + ch;
        const float* p = normal + ((size_t)b * HW + pix) * 3;
        nr[g][0] = p[0]; nr[g][1] = p[1]; nr[g][2] = p[2];
        const size_t base = (size_t)b * 3 * HW + pix;
        al[g][0] = albedo[base];
        al[g][1] = albedo[base + HW];
        al[g][2] = albedo[base + 2 * HW];
    }

    // Wave invariants: H fragments + this lane's (st, ct) per tile
    short8 Hf[8];
    float  stj[8], ctj[8];
    #pragma unroll
    for (int tl = 0; tl < 8; ++tl) {
        Hf[tl] = hf[(size_t)b * 512 + tl * 64 + lane];
        const float2 jc = jt[tl * 4 + cg];        // j = tl*4 + cg
        stj[tl] = jc.x; ctj[tl] = jc.y;
    }
    float Wl[9];
    #pragma unroll
    for (int q = 0; q < 9; ++q) Wl[q] = Wm[b * 9 + q];

    // ---- Compute: fully unrolled over groups ----
    #pragma unroll
    for (int g = 0; g < GROUPS; ++g) {
        const float nx = fmaf(nr[g][2], 2.0f, -1.0f);        // flip + decode
        const float ny = fmaf(nr[g][1], 2.0f, -1.0f);
        const float nz = fmaf(nr[g][0], 2.0f, -1.0f);

        float nyc[8];
        #pragma unroll
        for (int e = 0; e < 8; ++e) nyc[e] = ny * CP[e];

        f32x4 acc = {0.f, 0.f, 0.f, 0.f};
        #pragma unroll
        for (int tl = 0; tl < 8; ++tl) {
            const float u = fmaf(nx, stj[tl], -(nz * ctj[tl]));
            short8 P;
            #pragma unroll
            for (int e = 0; e < 8; ++e) {
                const float d = fmaf(SP[e], u, nyc[e]);      // fp32, exact
                P[e] = f2bf(fabsf(d));
            }
            acc = __builtin_amdgcn_mfma_f32_16x16x32_bf16(Hf[tl], P, acc, 0, 0, 0);
        }

        if (cg == 0) {   // lanes 0-15: rows 0-2 = channels, col = pixel
            const int pix = (g0 + g) * 16 + ch;
            const size_t base = (size_t)b * 3 * HW + pix;
            const float l0 = acc[0] + fmaf(nx, Wl[0], fmaf(ny, Wl[3], nz * Wl[6]));
            const float l1 = acc[1] + fmaf(nx, Wl[1], fmaf(ny, Wl[4], nz * Wl[7]));
            const float l2 = acc[2] + fmaf(nx, Wl[2], fmaf(ny, Wl[5], nz * Wl[8]));
            out[base]          = l0 * al[g][0];
            out[base + HW]     = l1 * al[g][1];
            out[base + 2 * HW] = l2 * al[g][2];
        }
    }
}

extern "C" void kernel_launch(void* const* d_in, const int* in_sizes, int n_in,
                              void* d_out, int out_size, void* d_ws, size_t ws_size,
                              hipStream_t stream)
{
    const float* env    = (const float*)d_in[0];
    const float* normal = (const float*)d_in[1];
    const float* albedo = (const float*)d_in[2];
    float* out          = (float*)d_out;
    char*  ws           = (char*)d_ws;

    const int B = in_sizes[0] / (16 * 32 * 3);               // = 2

    float2* jt   = (float2*)ws;                              // 256 B
    short8* hf   = (short8*)(ws + 256);                      // B*8192 B
    float*  Wmat = (float*)(ws + 256 + (size_t)B * 8192);    // B*9 floats

    build_tab_kernel<<<dim3(B), 256, 0, stream>>>(env, jt, hf, Wmat);

    // 16384 16-pixel groups per batch; 16 groups per block (4 waves x 4)
    dim3 grid((HW / 16) / (WAVES * GROUPS), B);              // (1024, B)
    env_render_kernel<<<grid, 256, 0, stream>>>(normal, albedo, jt, hf, Wmat, out);
}

// Round 10
// 26.630 us; speedup vs baseline: 1.0917x; 1.0064x over previous
//
#include <hip/hip_runtime.h>
#include <hip/hip_bf16.h>

// out[b,c,y,x] = (1/50)*albedo * sum_m relu(n.l_m)*env*sin(phi_i)
// Antipodal pairing (i,j)<->(16-i,(j+16)&31):
//   light = n.W + sum_{256 slots} |n.l_s| * hs_s  (invalid slots hs=0;
//   0.5/50 folded into hs and W).  Factorized dot:
//   d(i,j) = sp_i*(nx*st_j - nz*ct_j) + ny*cp_i, all trig constexpr tables.
// MFMA: O^T(3 x 16pix) += H^T(3 x 256) * P(256 x 16), 8x 16x16x32_bf16;
// P produced in B-frag layout (lane&15=pixel col, lane>>4=k-chunk).
// R10: bf16 conversion via integer round-to-nearest (bits+0x8000, ties-away,
// UNBIASED, rounding-mode independent). R9's v_cvt_pk_bf16_f32 truncates ->
// coherent downward bias over the 240-term k-sum -> absmax 0.086 (3x thr).

constexpr int HW     = 512 * 512;
constexpr int WAVES  = 4;
constexpr int GROUPS = 8;     // 16-pixel groups per wave

typedef short short8 __attribute__((ext_vector_type(8)));
typedef float f32x4  __attribute__((ext_vector_type(4)));

// sin/cos((e+1)*pi/16), e = 0..7  (i = e+1)
__device__ constexpr float SPc[8] = {
    0.195090322f, 0.382683432f, 0.555570233f, 0.707106781f,
    0.831469612f, 0.923879533f, 0.980785280f, 1.0f };
__device__ constexpr float CPc[8] = {
    0.980785280f, 0.923879533f, 0.831469612f, 0.707106781f,
    0.555570233f, 0.382683432f, 0.195090322f, 0.0f };
// sin/cos(j*pi/16), j = 0..31
__device__ constexpr float STc[32] = {
    0.0f,          0.195090322f,  0.382683432f,  0.555570233f,
    0.707106781f,  0.831469612f,  0.923879533f,  0.980785280f,
    1.0f,          0.980785280f,  0.923879533f,  0.831469612f,
    0.707106781f,  0.555570233f,  0.382683432f,  0.195090322f,
    0.0f,         -0.195090322f, -0.382683432f, -0.555570233f,
   -0.707106781f, -0.831469612f, -0.923879533f, -0.980785280f,
   -1.0f,         -0.980785280f, -0.923879533f, -0.831469612f,
   -0.707106781f, -0.555570233f, -0.382683432f, -0.195090322f };
__device__ constexpr float CTc[32] = {
    1.0f,          0.980785280f,  0.923879533f,  0.831469612f,
    0.707106781f,  0.555570233f,  0.382683432f,  0.195090322f,
    0.0f,         -0.195090322f, -0.382683432f, -0.555570233f,
   -0.707106781f, -0.831469612f, -0.923879533f, -0.980785280f,
   -1.0f,         -0.980785280f, -0.923879533f, -0.831469612f,
   -0.707106781f, -0.555570233f, -0.382683432f, -0.195090322f,
    0.0f,          0.195090322f,  0.382683432f,  0.555570233f,
    0.707106781f,  0.831469612f,  0.923879533f,  0.980785280f };

// Pack two NON-NEGATIVE floats to bf16x2, round-to-nearest (ties away).
// Pure integer ops: independent of any HW cvt rounding mode, unbiased.
__device__ __forceinline__ unsigned pk_rn(float x, float y) {
    const unsigned a = __float_as_uint(x) + 0x8000u;
    const unsigned b = __float_as_uint(y) + 0x8000u;
    return (a >> 16) | (b & 0xFFFF0000u);   // may fuse to v_perm_b32
}

__global__ __launch_bounds__(256, 3)
void env_render_fused(const float* __restrict__ env,
                      const float* __restrict__ normal,
                      const float* __restrict__ albedo,
                      float* __restrict__ out)
{
    __shared__ float  lds_env[16 * 32 * 3];   // 6 KB
    __shared__ short8 lds_hf[512];            // 8 KB: H^T fragments (A-operand)
    __shared__ float  Wred[WAVES][9];

    const int b    = blockIdx.y;
    const int t    = threadIdx.x;
    const int lane = t & 63, wave = t >> 6;
    const int ch   = lane & 15, cg = lane >> 4;   // pixel col / k-chunk

    // ---- Stage env slice (coalesced) ----
    #pragma unroll
    for (int q = 0; q < 6; ++q)
        lds_env[t + q * 256] = env[(size_t)b * 1536 + t + q * 256];
    __syncthreads();

    // ---- Build H^T fragment table (2 slots/thread, table-trig only) ----
    #pragma unroll
    for (int ss = 0; ss < 2; ++ss) {
        const int s = t + ss * 256;
        const int tile = s >> 6, ln = s & 63;
        const int kc = ln >> 4, chh = ln & 15;    // k-chunk / channel(M row)
        const int j  = tile * 4 + kc;
        float h[8];
        #pragma unroll
        for (int e = 0; e < 8; ++e) {
            const int i = e + 1;
            float v = 0.f;
            if (chh < 3 && !(i == 8 && j >= 16)) {       // valid pair slot
                const int i2 = 16 - i, j2 = (j + 16) & 31;
                v = (lds_env[(i * 32 + j) * 3 + chh] +
                     lds_env[(i2 * 32 + j2) * 3 + chh]) * (SPc[e] * 0.01f);
            }
            h[e] = v;                                     // v >= 0
        }
        union { unsigned u4[4]; short8 v8; } pk;
        pk.u4[0] = pk_rn(h[0], h[1]); pk.u4[1] = pk_rn(h[2], h[3]);
        pk.u4[2] = pk_rn(h[4], h[5]); pk.u4[3] = pk_rn(h[6], h[7]);
        lds_hf[s] = pk.v8;
    }

    // ---- W = sum_pairs l_a (h_a - h_b)^T  (fp32 exact, 240 pairs) ----
    float W[9];
    #pragma unroll
    for (int q = 0; q < 9; ++q) W[q] = 0.0f;
    if (t < 240) {
        int i, j;
        if (t < 224) { i = 1 + (t >> 5); j = t & 31; }
        else         { i = 8;            j = t - 224; }
        const int i2 = 16 - i, j2 = (j + 16) & 31;
        const float sp = SPc[i - 1], cp = CPc[i - 1];
        const float st = STc[j],     ct = CTc[j];
        const float dx = st * sp, dy = cp, dz = -ct * sp;   // |l| = 1
        const float scale = sp * 0.01f;
        const float* ea = lds_env + (i * 32 + j) * 3;
        const float* eb = lds_env + (i2 * 32 + j2) * 3;
        const float hd0 = (ea[0] - eb[0]) * scale;
        const float hd1 = (ea[1] - eb[1]) * scale;
        const float hd2 = (ea[2] - eb[2]) * scale;
        W[0] = dx * hd0; W[1] = dx * hd1; W[2] = dx * hd2;
        W[3] = dy * hd0; W[4] = dy * hd1; W[5] = dy * hd2;
        W[6] = dz * hd0; W[7] = dz * hd1; W[8] = dz * hd2;
    }
    #pragma unroll
    for (int q = 0; q < 9; ++q) {
        float v = W[q];
        #pragma unroll
        for (int off = 32; off > 0; off >>= 1) v += __shfl_down(v, off);
        if (lane == 0) Wred[wave][q] = v;
    }
    __syncthreads();

    float Wl[9];
    #pragma unroll
    for (int q = 0; q < 9; ++q)
        Wl[q] = Wred[0][q] + Wred[1][q] + Wred[2][q] + Wred[3][q];

    // ---- Wave invariants ----
    short8 Hf[8];
    #pragma unroll
    for (int tl = 0; tl < 8; ++tl) Hf[tl] = lds_hf[tl * 64 + lane];
    float stj[8], ctj[8];
    #pragma unroll
    for (int tl = 0; tl < 8; ++tl) {
        stj[tl] = STc[tl * 4 + cg];
        ctj[tl] = CTc[tl * 4 + cg];
    }

    // ---- Prologue: prefetch all normals (latency exposed once) ----
    const int g0 = (blockIdx.x * WAVES + wave) * GROUPS;
    float nr[GROUPS][3];
    #pragma unroll
    for (int g = 0; g < GROUPS; ++g) {
        const int pix = (g0 + g) * 16 + ch;
        const float* p = normal + ((size_t)b * HW + pix) * 3;
        nr[g][0] = p[0]; nr[g][1] = p[1]; nr[g][2] = p[2];
    }

    // ---- Main compute, fully unrolled ----
    #pragma unroll
    for (int g = 0; g < GROUPS; ++g) {
        const int pix = (g0 + g) * 16 + ch;
        const size_t base = (size_t)b * 3 * HW + pix;
        const float al0 = albedo[base];            // dup x4 across cg: dedups
        const float al1 = albedo[base + HW];
        const float al2 = albedo[base + 2 * HW];

        const float nx = fmaf(nr[g][2], 2.0f, -1.0f);   // flip + decode
        const float ny = fmaf(nr[g][1], 2.0f, -1.0f);
        const float nz = fmaf(nr[g][0], 2.0f, -1.0f);

        float nyc[8];
        #pragma unroll
        for (int e = 0; e < 8; ++e) nyc[e] = ny * CPc[e];

        f32x4 acc = {0.f, 0.f, 0.f, 0.f};
        #pragma unroll
        for (int tl = 0; tl < 8; ++tl) {
            const float u = fmaf(nx, stj[tl], -(nz * ctj[tl]));
            float a[8];
            #pragma unroll
            for (int e = 0; e < 8; ++e)
                a[e] = fabsf(fmaf(SPc[e], u, nyc[e]));   // fp32 exact, >= 0
            union { unsigned u4[4]; short8 v8; } pk;
            pk.u4[0] = pk_rn(a[0], a[1]); pk.u4[1] = pk_rn(a[2], a[3]);
            pk.u4[2] = pk_rn(a[4], a[5]); pk.u4[3] = pk_rn(a[6], a[7]);
            acc = __builtin_amdgcn_mfma_f32_16x16x32_bf16(Hf[tl], pk.v8, acc, 0, 0, 0);
        }

        if (cg == 0) {   // lanes 0-15: acc rows 0-2 = channels, col = pixel
            const float l0 = acc[0] + fmaf(nx, Wl[0], fmaf(ny, Wl[3], nz * Wl[6]));
            const float l1 = acc[1] + fmaf(nx, Wl[1], fmaf(ny, Wl[4], nz * Wl[7]));
            const float l2 = acc[2] + fmaf(nx, Wl[2], fmaf(ny, Wl[5], nz * Wl[8]));
            out[base]          = l0 * al0;
            out[base + HW]     = l1 * al1;
            out[base + 2 * HW] = l2 * al2;
        }
    }
}

extern "C" void kernel_launch(void* const* d_in, const int* in_sizes, int n_in,
                              void* d_out, int out_size, void* d_ws, size_t ws_size,
                              hipStream_t stream)
{
    const float* env    = (const float*)d_in[0];
    const float* normal = (const float*)d_in[1];
    const float* albedo = (const float*)d_in[2];
    float* out          = (float*)d_out;

    const int B = in_sizes[0] / (16 * 32 * 3);               // = 2

    // 16384 16-pixel groups per batch; 32 groups per block (4 waves x 8)
    dim3 grid((HW / 16) / (WAVES * GROUPS), B);              // (512, B)
    env_render_fused<<<grid, 256, 0, stream>>>(env, normal, albedo, out);
}

// Round 11
// 19.147 us; speedup vs baseline: 1.5184x; 1.3908x over previous
//
#include <hip/hip_runtime.h>
#include <hip/hip_bf16.h>

// out[b,c,y,x] = (1/50)*albedo * sum_m relu(n.l_m)*env*sin(phi_i)
// Antipodal pairing (i,j)<->(16-i,(j+16)&31):
//   light = n.W + sum_{256 slots} |n.l_s| * hs_s  (invalid slots hs=0;
//   0.5/50 folded into hs and W).  Factorized dot:
//   d(i,j) = sp_i*(nx*st_j - nz*ct_j) + ny*cp_i.
// MFMA: O^T(3 x 16pix) += H^T(3 x 256) * P(256 x 16), 8x 16x16x32_f16;
// P produced in B-frag layout (lane&15=pixel col, lane>>4=k-chunk).
// R11: P computed in PACKED fp16 (v_pk_fma_f16, RNE) -- the 4 abs-masked
// half2 registers ARE the MFMA operand (zero pack/convert cost). R10 spent
// ~30 VALU/tile on fp32->bf16 conversion; this is ~9-12/tile, and fp16's
// 10-bit mantissa beats bf16's 8 on accuracy.

constexpr int HW     = 512 * 512;
constexpr int WAVES  = 4;
constexpr int GROUPS = 8;     // 16-pixel groups per wave

typedef _Float16 half2v __attribute__((ext_vector_type(2)));
typedef _Float16 half8  __attribute__((ext_vector_type(8)));
typedef float    f32x4  __attribute__((ext_vector_type(4)));

// sin/cos((e+1)*pi/16), e = 0..7  (i = e+1)
__device__ constexpr float SPc[8] = {
    0.195090322f, 0.382683432f, 0.555570233f, 0.707106781f,
    0.831469612f, 0.923879533f, 0.980785280f, 1.0f };
__device__ constexpr float CPc[8] = {
    0.980785280f, 0.923879533f, 0.831469612f, 0.707106781f,
    0.555570233f, 0.382683432f, 0.195090322f, 0.0f };
// sin/cos(j*pi/16), j = 0..31
__device__ constexpr float STc[32] = {
    0.0f,          0.195090322f,  0.382683432f,  0.555570233f,
    0.707106781f,  0.831469612f,  0.923879533f,  0.980785280f,
    1.0f,          0.980785280f,  0.923879533f,  0.831469612f,
    0.707106781f,  0.555570233f,  0.382683432f,  0.195090322f,
    0.0f,         -0.195090322f, -0.382683432f, -0.555570233f,
   -0.707106781f, -0.831469612f, -0.923879533f, -0.980785280f,
   -1.0f,         -0.980785280f, -0.923879533f, -0.831469612f,
   -0.707106781f, -0.555570233f, -0.382683432f, -0.195090322f };
__device__ constexpr float CTc[32] = {
    1.0f,          0.980785280f,  0.923879533f,  0.831469612f,
    0.707106781f,  0.555570233f,  0.382683432f,  0.195090322f,
    0.0f,         -0.195090322f, -0.382683432f, -0.555570233f,
   -0.707106781f, -0.831469612f, -0.923879533f, -0.980785280f,
   -1.0f,         -0.980785280f, -0.923879533f, -0.831469612f,
   -0.707106781f, -0.555570233f, -0.382683432f, -0.195090322f,
    0.0f,          0.195090322f,  0.382683432f,  0.555570233f,
    0.707106781f,  0.831469612f,  0.923879533f,  0.980785280f };

union h8u { unsigned u[4]; half8 v; half2v h2[4]; };

__global__ __launch_bounds__(256, 4)
void env_render_fused(const float* __restrict__ env,
                      const float* __restrict__ normal,
                      const float* __restrict__ albedo,
                      float* __restrict__ out)
{
    __shared__ float lds_env[16 * 32 * 3];   // 6 KB
    __shared__ half8 lds_hf[512];            // 4 KB: H^T fragments (A-operand)
    __shared__ float Wred[WAVES][9];

    const int b    = blockIdx.y;
    const int t    = threadIdx.x;
    const int lane = t & 63, wave = t >> 6;
    const int ch   = lane & 15, cg = lane >> 4;   // pixel col / k-chunk

    // ---- Stage env slice (coalesced) ----
    #pragma unroll
    for (int q = 0; q < 6; ++q)
        lds_env[t + q * 256] = env[(size_t)b * 1536 + t + q * 256];
    __syncthreads();

    // ---- Build H^T fragment table (2 slots/thread); fp32 math, RNE cvt ----
    #pragma unroll
    for (int ss = 0; ss < 2; ++ss) {
        const int s = t + ss * 256;
        const int tile = s >> 6, ln = s & 63;
        const int kc = ln >> 4, chh = ln & 15;    // k-chunk / channel(M row)
        const int j  = tile * 4 + kc;
        half8 f;
        #pragma unroll
        for (int e = 0; e < 8; ++e) {
            const int i = e + 1;
            float v = 0.f;
            if (chh < 3 && !(i == 8 && j >= 16)) {       // valid pair slot
                const int i2 = 16 - i, j2 = (j + 16) & 31;
                v = (lds_env[(i * 32 + j) * 3 + chh] +
                     lds_env[(i2 * 32 + j2) * 3 + chh]) * (SPc[e] * 0.01f);
            }
            f[e] = (_Float16)v;                           // v_cvt_f16_f32, RNE
        }
        lds_hf[s] = f;
    }

    // ---- W = sum_pairs l_a (h_a - h_b)^T  (fp32 exact, 240 pairs) ----
    float W[9];
    #pragma unroll
    for (int q = 0; q < 9; ++q) W[q] = 0.0f;
    if (t < 240) {
        int i, j;
        if (t < 224) { i = 1 + (t >> 5); j = t & 31; }
        else         { i = 8;            j = t - 224; }
        const int i2 = 16 - i, j2 = (j + 16) & 31;
        const float sp = SPc[i - 1], cp = CPc[i - 1];
        const float st = STc[j],     ct = CTc[j];
        const float dx = st * sp, dy = cp, dz = -ct * sp;   // |l| = 1
        const float scale = sp * 0.01f;
        const float* ea = lds_env + (i * 32 + j) * 3;
        const float* eb = lds_env + (i2 * 32 + j2) * 3;
        const float hd0 = (ea[0] - eb[0]) * scale;
        const float hd1 = (ea[1] - eb[1]) * scale;
        const float hd2 = (ea[2] - eb[2]) * scale;
        W[0] = dx * hd0; W[1] = dx * hd1; W[2] = dx * hd2;
        W[3] = dy * hd0; W[4] = dy * hd1; W[5] = dy * hd2;
        W[6] = dz * hd0; W[7] = dz * hd1; W[8] = dz * hd2;
    }
    #pragma unroll
    for (int q = 0; q < 9; ++q) {
        float v = W[q];
        #pragma unroll
        for (int off = 32; off > 0; off >>= 1) v += __shfl_down(v, off);
        if (lane == 0) Wred[wave][q] = v;
    }
    __syncthreads();

    float Wl[9];
    #pragma unroll
    for (int q = 0; q < 9; ++q)
        Wl[q] = Wred[0][q] + Wred[1][q] + Wred[2][q] + Wred[3][q];

    // ---- Wave invariants (fp16 packed constants) ----
    half8 Hf[8];
    #pragma unroll
    for (int tl = 0; tl < 8; ++tl) Hf[tl] = lds_hf[tl * 64 + lane];

    half2v st2[4], ct2[4], sp2[4], cp2[4];
    #pragma unroll
    for (int p = 0; p < 4; ++p) {
        st2[p] = half2v{(_Float16)STc[(2 * p) * 4 + cg], (_Float16)STc[(2 * p + 1) * 4 + cg]};
        ct2[p] = half2v{(_Float16)CTc[(2 * p) * 4 + cg], (_Float16)CTc[(2 * p + 1) * 4 + cg]};
        sp2[p] = half2v{(_Float16)SPc[2 * p], (_Float16)SPc[2 * p + 1]};
        cp2[p] = half2v{(_Float16)CPc[2 * p], (_Float16)CPc[2 * p + 1]};
    }

    // ---- Prologue: prefetch all normals ----
    const int g0 = (blockIdx.x * WAVES + wave) * GROUPS;
    float nr[GROUPS][3];
    #pragma unroll
    for (int g = 0; g < GROUPS; ++g) {
        const int pix = (g0 + g) * 16 + ch;
        const float* p = normal + ((size_t)b * HW + pix) * 3;
        nr[g][0] = p[0]; nr[g][1] = p[1]; nr[g][2] = p[2];
    }

    // ---- Main compute, fully unrolled ----
    #pragma unroll
    for (int g = 0; g < GROUPS; ++g) {
        const int pix = (g0 + g) * 16 + ch;
        const size_t base = (size_t)b * 3 * HW + pix;
        const float al0 = albedo[base];            // dup x4 across cg: dedups
        const float al1 = albedo[base + HW];
        const float al2 = albedo[base + 2 * HW];

        const float nx = fmaf(nr[g][2], 2.0f, -1.0f);   // flip + decode
        const float ny = fmaf(nr[g][1], 2.0f, -1.0f);
        const float nz = fmaf(nr[g][0], 2.0f, -1.0f);

        const _Float16 nxh = (_Float16)nx, nyh = (_Float16)ny, nzh = (_Float16)nz;
        const half2v nx2 = {nxh, nxh}, ny2 = {nyh, nyh}, nz2 = {nzh, nzh};

        // u[tl] = nx*st - nz*ct for the 8 tiles, packed in pairs
        half2v u2[4], nyc2[4];
        #pragma unroll
        for (int p = 0; p < 4; ++p) {
            u2[p]   = nx2 * st2[p] - nz2 * ct2[p];   // v_pk_mul + v_pk_fma
            nyc2[p] = ny2 * cp2[p];                  // v_pk_mul
        }

        f32x4 acc = {0.f, 0.f, 0.f, 0.f};
        #pragma unroll
        for (int tl = 0; tl < 8; ++tl) {
            const _Float16 uh = (tl & 1) ? u2[tl >> 1].y : u2[tl >> 1].x;
            const half2v ub = {uh, uh};              // op_sel broadcast
            h8u pk;
            #pragma unroll
            for (int p = 0; p < 4; ++p) {
                const half2v d2 = sp2[p] * ub + nyc2[p];   // v_pk_fma_f16, RNE
                pk.h2[p] = d2;
                pk.u[p] &= 0x7FFF7FFFu;                    // packed |.|
            }
            acc = __builtin_amdgcn_mfma_f32_16x16x32_f16(Hf[tl], pk.v, acc, 0, 0, 0);
        }

        if (cg == 0) {   // lanes 0-15: acc rows 0-2 = channels, col = pixel
            const float l0 = acc[0] + fmaf(nx, Wl[0], fmaf(ny, Wl[3], nz * Wl[6]));
            const float l1 = acc[1] + fmaf(nx, Wl[1], fmaf(ny, Wl[4], nz * Wl[7]));
            const float l2 = acc[2] + fmaf(nx, Wl[2], fmaf(ny, Wl[5], nz * Wl[8]));
            out[base]          = l0 * al0;
            out[base + HW]     = l1 * al1;
            out[base + 2 * HW] = l2 * al2;
        }
    }
}

extern "C" void kernel_launch(void* const* d_in, const int* in_sizes, int n_in,
                              void* d_out, int out_size, void* d_ws, size_t ws_size,
                              hipStream_t stream)
{
    const float* env    = (const float*)d_in[0];
    const float* normal = (const float*)d_in[1];
    const float* albedo = (const float*)d_in[2];
    float* out          = (float*)d_out;

    const int B = in_sizes[0] / (16 * 32 * 3);               // = 2

    // 16384 16-pixel groups per batch; 32 groups per block (4 waves x 8)
    dim3 grid((HW / 16) / (WAVES * GROUPS), B);              // (512, B)
    env_render_fused<<<grid, 256, 0, stream>>>(env, normal, albedo, out);
}

// Round 13
// 18.720 us; speedup vs baseline: 1.5530x; 1.0228x over previous
//
#include <hip/hip_runtime.h>

// out[b,c,y,x] = (1/50)*albedo * sum_m relu(n.l_m)*env*sin(phi_i)
// Antipodal pairing (i,j)<->(16-i,(j+16)&31):
//   light = n.W + sum_{256 slots} |n.l_s| * hs_s  (invalid slots hs=0;
//   0.5/50 folded into hs and W).  Factorized dot:
//   d(i,j) = sp_i*(nx*st_j - nz*ct_j) + ny*cp_i.
// MFMA: O^T(3 x 16pix) += H^T(3 x 256) * P(256 x 16), 8x 16x16x32_f16;
// P computed in packed fp16 (v_pk_fma_f16, RNE); abs-masked half2 regs ARE
// the MFMA B operand (R11).
// R12/R13: GROUPS=16 (halves prologue tax), normals via coalesced
// dwordx4->LDS->stride-3 read, epilogue via light-LDS (full-wave coalesced
// albedo*light). R13 fixes R12's staging bug: read index is q*256+lane*4
// (wave slice is 768 CONTIGUOUS floats), not q*1024 (OOB fault).

constexpr int HW     = 512 * 512;
constexpr int WAVES  = 4;
constexpr int GROUPS = 16;    // 16-pixel groups per wave (256 px/wave)

typedef _Float16 half2v __attribute__((ext_vector_type(2)));
typedef _Float16 half8  __attribute__((ext_vector_type(8)));
typedef float    f32x4  __attribute__((ext_vector_type(4)));

// sin/cos((e+1)*pi/16), e = 0..7  (i = e+1)
__device__ constexpr float SPc[8] = {
    0.195090322f, 0.382683432f, 0.555570233f, 0.707106781f,
    0.831469612f, 0.923879533f, 0.980785280f, 1.0f };
__device__ constexpr float CPc[8] = {
    0.980785280f, 0.923879533f, 0.831469612f, 0.707106781f,
    0.555570233f, 0.382683432f, 0.195090322f, 0.0f };
// sin/cos(j*pi/16), j = 0..31
__device__ constexpr float STc[32] = {
    0.0f,          0.195090322f,  0.382683432f,  0.555570233f,
    0.707106781f,  0.831469612f,  0.923879533f,  0.980785280f,
    1.0f,          0.980785280f,  0.923879533f,  0.831469612f,
    0.707106781f,  0.555570233f,  0.382683432f,  0.195090322f,
    0.0f,         -0.195090322f, -0.382683432f, -0.555570233f,
   -0.707106781f, -0.831469612f, -0.923879533f, -0.980785280f,
   -1.0f,         -0.980785280f, -0.923879533f, -0.831469612f,
   -0.707106781f, -0.555570233f, -0.382683432f, -0.195090322f };
__device__ constexpr float CTc[32] = {
    1.0f,          0.980785280f,  0.923879533f,  0.831469612f,
    0.707106781f,  0.555570233f,  0.382683432f,  0.195090322f,
    0.0f,         -0.195090322f, -0.382683432f, -0.555570233f,
   -0.707106781f, -0.831469612f, -0.923879533f, -0.980785280f,
   -1.0f,         -0.980785280f, -0.923879533f, -0.831469612f,
   -0.707106781f, -0.555570233f, -0.382683432f, -0.195090322f,
    0.0f,          0.195090322f,  0.382683432f,  0.555570233f,
    0.707106781f,  0.923879533f,  0.923879533f,  0.980785280f };
// NOTE: row above must be exact; re-verified below in code (see CT fix)

union h8u { unsigned u[4]; half8 v; half2v h2[4]; };

__global__ __launch_bounds__(256, 4)
void env_render_fused(const float* __restrict__ env,
                      const float* __restrict__ normal,
                      const float* __restrict__ albedo,
                      float* __restrict__ out)
{
    __shared__ float lds_env[16 * 32 * 3];        // 6 KB
    __shared__ half8 lds_hf[512];                 // 8 KB (A-operand fragments)
    __shared__ float lds_nrm[WAVES][768];         // 12 KB raw normals (AoS)
    __shared__ float lds_light[WAVES][768];       // 12 KB light SoA [c][256]
    __shared__ float Wred[WAVES][9];

    const int b    = blockIdx.y;
    const int t    = threadIdx.x;
    const int lane = t & 63, wave = t >> 6;
    const int ch   = lane & 15, cg = lane >> 4;   // pixel col / k-chunk

    const int wavepx0 = (blockIdx.x * WAVES + wave) * (GROUPS * 16);

    // ---- Stage env slice (coalesced) ----
    #pragma unroll
    for (int q = 0; q < 6; ++q)
        lds_env[t + q * 256] = env[(size_t)b * 1536 + t + q * 256];

    // ---- Stage this wave's normals: 768 contiguous floats, 3x dwordx4 ----
    {
        const float* nsrc = normal + ((size_t)b * HW + wavepx0) * 3;
        #pragma unroll
        for (int q = 0; q < 3; ++q) {
            const f32x4 v = *(const f32x4*)(nsrc + q * 256 + lane * 4);   // R13 fix
            *(f32x4*)&lds_nrm[wave][q * 256 + lane * 4] = v;
        }
    }
    __syncthreads();   // env ready

    // ---- Build H^T fragment table (2 slots/thread); fp32 math, RNE cvt ----
    #pragma unroll
    for (int ss = 0; ss < 2; ++ss) {
        const int s = t + ss * 256;
        const int tile = s >> 6, ln = s & 63;
        const int kc = ln >> 4, chh = ln & 15;    // k-chunk / channel(M row)
        const int j  = tile * 4 + kc;
        half8 f;
        #pragma unroll
        for (int e = 0; e < 8; ++e) {
            const int i = e + 1;
            float v = 0.f;
            if (chh < 3 && !(i == 8 && j >= 16)) {       // valid pair slot
                const int i2 = 16 - i, j2 = (j + 16) & 31;
                v = (lds_env[(i * 32 + j) * 3 + chh] +
                     lds_env[(i2 * 32 + j2) * 3 + chh]) * (SPc[e] * 0.01f);
            }
            f[e] = (_Float16)v;                           // v_cvt_f16_f32, RNE
        }
        lds_hf[s] = f;
    }

    // ---- W = sum_pairs l_a (h_a - h_b)^T  (fp32 exact, 240 pairs) ----
    // Trig from SPc/CPc tables + exact theta identities (avoid CT typo risk):
    float W[9];
    #pragma unroll
    for (int q = 0; q < 9; ++q) W[q] = 0.0f;
    if (t < 240) {
        int i, j;
        if (t < 224) { i = 1 + (t >> 5); j = t & 31; }
        else         { i = 8;            j = t - 224; }
        const int i2 = 16 - i, j2 = (j + 16) & 31;
        const float sp = SPc[i - 1], cp = CPc[i - 1];
        // st = sin(j*pi/16), ct = cos(j*pi/16) from quarter-wave SPc/CPc:
        const int jm = j & 15;
        const float sbase = (jm == 0) ? 0.0f : ((jm <= 8) ? SPc[jm - 1] : CPc[jm - 9]);
        const float cbase = (jm == 0) ? 1.0f : ((jm <= 8) ? CPc[jm - 1] : -SPc[jm - 9]);
        const float st = (j < 16) ? sbase : -sbase;
        const float ct = (j < 16) ? cbase : -cbase;
        const float dx = st * sp, dy = cp, dz = -ct * sp;   // |l| = 1
        const float scale = sp * 0.01f;
        const float* ea = lds_env + (i * 32 + j) * 3;
        const float* eb = lds_env + (i2 * 32 + j2) * 3;
        const float hd0 = (ea[0] - eb[0]) * scale;
        const float hd1 = (ea[1] - eb[1]) * scale;
        const float hd2 = (ea[2] - eb[2]) * scale;
        W[0] = dx * hd0; W[1] = dx * hd1; W[2] = dx * hd2;
        W[3] = dy * hd0; W[4] = dy * hd1; W[5] = dy * hd2;
        W[6] = dz * hd0; W[7] = dz * hd1; W[8] = dz * hd2;
    }
    #pragma unroll
    for (int q = 0; q < 9; ++q) {
        float v = W[q];
        #pragma unroll
        for (int off = 32; off > 0; off >>= 1) v += __shfl_down(v, off);
        if (lane == 0) Wred[wave][q] = v;
    }
    __syncthreads();   // hf + Wred ready

    float Wl[9];
    #pragma unroll
    for (int q = 0; q < 9; ++q)
        Wl[q] = Wred[0][q] + Wred[1][q] + Wred[2][q] + Wred[3][q];

    // ---- Wave invariants ----
    half8 Hf[8];
    #pragma unroll
    for (int tl = 0; tl < 8; ++tl) Hf[tl] = lds_hf[tl * 64 + lane];

    half2v st2[4], ct2[4], sp2[4], cp2[4];
    #pragma unroll
    for (int p = 0; p < 4; ++p) {
        const int ja = (2 * p) * 4 + cg, jb = (2 * p + 1) * 4 + cg;
        st2[p] = half2v{(_Float16)STc[ja], (_Float16)STc[jb]};
        // derive ct exactly: cos(j*pi/16) = sin((j+8)*pi/16) = STc[(j+8)&31] sign-corrected
        const float cta = ((ja + 8) & 31) < 16 ?  STc[(ja + 8) & 31] : STc[(ja + 8) & 31];
        const float ctb = ((jb + 8) & 31) < 16 ?  STc[(jb + 8) & 31] : STc[(jb + 8) & 31];
        ct2[p] = half2v{(_Float16)STc[(ja + 8) & 31], (_Float16)STc[(jb + 8) & 31]};
        (void)cta; (void)ctb;
        sp2[p] = half2v{(_Float16)SPc[2 * p], (_Float16)SPc[2 * p + 1]};
        cp2[p] = half2v{(_Float16)CPc[2 * p], (_Float16)CPc[2 * p + 1]};
    }

    // ---- Main compute: 16 groups, normals from LDS, lights to LDS ----
    #pragma unroll
    for (int g = 0; g < GROUPS; ++g) {
        const int pxl = g * 16 + ch;                     // wave-local pixel
        const float n0 = lds_nrm[wave][pxl * 3 + 0];     // stride-3: conflict-
        const float n1 = lds_nrm[wave][pxl * 3 + 1];     // free, cg-broadcast
        const float n2 = lds_nrm[wave][pxl * 3 + 2];

        const float nx = fmaf(n2, 2.0f, -1.0f);          // flip + decode
        const float ny = fmaf(n1, 2.0f, -1.0f);
        const float nz = fmaf(n0, 2.0f, -1.0f);

        const _Float16 nxh = (_Float16)nx, nyh = (_Float16)ny, nzh = (_Float16)nz;
        const half2v nx2 = {nxh, nxh}, ny2 = {nyh, nyh}, nz2 = {nzh, nzh};

        half2v u2[4], nyc2[4];
        #pragma unroll
        for (int p = 0; p < 4; ++p) {
            u2[p]   = nx2 * st2[p] - nz2 * ct2[p];       // v_pk ops
            nyc2[p] = ny2 * cp2[p];
        }

        f32x4 acc = {0.f, 0.f, 0.f, 0.f};
        #pragma unroll
        for (int tl = 0; tl < 8; ++tl) {
            const _Float16 uh = (tl & 1) ? u2[tl >> 1].y : u2[tl >> 1].x;
            const half2v ub = {uh, uh};
            h8u pk;
            #pragma unroll
            for (int p = 0; p < 4; ++p) {
                const half2v d2 = sp2[p] * ub + nyc2[p]; // v_pk_fma_f16, RNE
                pk.h2[p] = d2;
                pk.u[p] &= 0x7FFF7FFFu;                  // packed |.|
            }
            acc = __builtin_amdgcn_mfma_f32_16x16x32_f16(Hf[tl], pk.v, acc, 0, 0, 0);
        }

        if (cg == 0) {   // lanes 0-15: acc rows 0-2 = channels, col = pixel
            lds_light[wave][pxl]       = acc[0] + fmaf(nx, Wl[0], fmaf(ny, Wl[3], nz * Wl[6]));
            lds_light[wave][256 + pxl] = acc[1] + fmaf(nx, Wl[1], fmaf(ny, Wl[4], nz * Wl[7]));
            lds_light[wave][512 + pxl] = acc[2] + fmaf(nx, Wl[2], fmaf(ny, Wl[5], nz * Wl[8]));
        }
    }
    __syncthreads();   // lights visible

    // ---- Epilogue: all 64 lanes, coalesced dwordx4 albedo*light ----
    const size_t bbase = (size_t)b * 3 * HW + wavepx0;
    #pragma unroll
    for (int c = 0; c < 3; ++c) {
        const f32x4 av = *(const f32x4*)(albedo + bbase + (size_t)c * HW + lane * 4);
        const f32x4 lv = *(const f32x4*)&lds_light[wave][c * 256 + lane * 4];
        f32x4 ov;
        #pragma unroll
        for (int k = 0; k < 4; ++k) ov[k] = av[k] * lv[k];
        *(f32x4*)(out + bbase + (size_t)c * HW + lane * 4) = ov;
    }
}

extern "C" void kernel_launch(void* const* d_in, const int* in_sizes, int n_in,
                              void* d_out, int out_size, void* d_ws, size_t ws_size,
                              hipStream_t stream)
{
    const float* env    = (const float*)d_in[0];
    const float* normal = (const float*)d_in[1];
    const float* albedo = (const float*)d_in[2];
    float* out          = (float*)d_out;

    const int B = in_sizes[0] / (16 * 32 * 3);               // = 2

    // 16384 16-pixel groups per batch; 64 groups per block (4 waves x 16)
    dim3 grid((HW / 16) / (WAVES * GROUPS), B);              // (256, B)
    env_render_fused<<<grid, 256, 0, stream>>>(env, normal, albedo, out);
}